// Round 2
// 2875.623 us; speedup vs baseline: 1.8789x; 1.8789x over previous
//
#include <hip/hip_runtime.h>
#include <hip/hip_bf16.h>

typedef unsigned short u16;
typedef unsigned int   u32;
typedef unsigned long long u64;
typedef __attribute__((ext_vector_type(4))) float f32x4;
typedef __attribute__((ext_vector_type(8))) short bf16x8;

#define SEQ 512
#define IND 512
#define HID 256
#define WROW 768
#define WGELEM (HID*WROW)              // 196608 elems per gate weight

// workspace byte offsets (all 256-aligned)
#define OFF_FLAG 0
#define OFF_CNT  256                                   // arrival counters [SEQ+8][16] int = 33280 B
#define CNT_INTS (520*16)
#define OFF_WC   (OFF_CNT + CNT_INTS*4)                // canonical W bf16, 4*196608*2 = 1572864
#define OFF_BR   (OFF_WC + 4*WGELEM*2)                 // bias+rot f32, 4096
#define OFF_HB   (OFF_BR + 4*HID*4)                    // h exchange, bf16 [2][256][256] = 262144
#define OFF_CST  (OFF_HB + 2*HID*HID*2)                // c state f32 [256][256] = 262144
#define OFF_XW   (OFF_CST + HID*HID*4)                 // xw chunk buffer, bf16 [ns*256][1024]
#define XW_STEP_BYTES (HID*4*HID*2)                    // 524288 B per timestep

__device__ __forceinline__ float bf2f(u16 u) {
    union { u32 i; float f; } v; v.i = ((u32)u) << 16; return v.f;
}
__device__ __forceinline__ u16 f2bf(float f) {
    union { float f; u32 i; } v; v.f = f;
    u32 x = v.i;
    x += 0x7fff + ((x >> 16) & 1);   // RNE
    return (u16)(x >> 16);
}
__device__ __forceinline__ float sigm(float x) {
    return 1.f / (1.f + __expf(-x));
}
__device__ __forceinline__ float tanh_fast(float x) {
    float xc = fminf(fmaxf(x, -15.f), 15.f);   // |c| reaches ~450; clamp avoids inf/inf
    float e = __expf(2.f * xc);
    return 1.f - 2.f / (e + 1.f);
}

// dtype sniff on rf ~ N(0,1): bf16 stream -> nearly all 128 words have sane exponent;
// fp32 stream read as u16 -> only the 64 odd (high-half) words do.
__device__ __forceinline__ int sniff_is_bf16(const u16* p) {
    int cnt = 0;
    for (int i = 0; i < 128; ++i) {
        int e = (p[i] >> 7) & 0xFF;
        cnt += (e >= 110 && e <= 135) ? 1 : 0;
    }
    return (cnt >= 112) ? 1 : 0;
}

// ------------- Kernel 0: sniff dtype; canonicalize W (bf16), bias+rot (f32); zero sync counters --
__global__ __launch_bounds__(256) void convert_w(
    const void* W0, const void* W1, const void* W2, const void* W3,
    const void* B0, const void* B1, const void* B2, const void* B3,
    const void* R0, const void* R1, const void* R2, const void* R3,
    char* ws)
{
    __shared__ int sflag;
    const int tid = threadIdx.x;
    if (tid == 0) sflag = sniff_is_bf16((const u16*)R0);
    __syncthreads();
    const int flag = sflag;

    const int g = blockIdx.y;
    const void* Wsrc = (g==0)?W0:(g==1)?W1:(g==2)?W2:W3;
    const void* Bsrc = (g==0)?B0:(g==1)?B1:(g==2)?B2:B3;
    const void* Rsrc = (g==0)?R0:(g==1)?R1:(g==2)?R2:R3;
    u16*   Wc = (u16*)(ws + OFF_WC) + (size_t)g * WGELEM;
    float* br = (float*)(ws + OFF_BR);

    if (g == 0) {                                   // zero arrival counters (ws is re-poisoned)
        int idx = blockIdx.x * 256 + tid;
        if (idx < CNT_INTS) ((int*)(ws + OFF_CNT))[idx] = 0;
    }

    const size_t i = ((size_t)blockIdx.x * 256 + tid) * 8;
    if (flag) {
        *(uint4*)(Wc + i) = *(const uint4*)((const u16*)Wsrc + i);
    } else {
        const float* s = (const float*)Wsrc + i;
        float4 a = *(const float4*)s;
        float4 b = *(const float4*)(s + 4);
        u32 w0 = (u32)f2bf(a.x) | ((u32)f2bf(a.y) << 16);
        u32 w1 = (u32)f2bf(a.z) | ((u32)f2bf(a.w) << 16);
        u32 w2 = (u32)f2bf(b.x) | ((u32)f2bf(b.y) << 16);
        u32 w3 = (u32)f2bf(b.z) | ((u32)f2bf(b.w) << 16);
        *(uint4*)(Wc + i) = make_uint4(w0, w1, w2, w3);
    }
    if (blockIdx.x == 0) {
        float bv, rv;
        if (flag) { bv = bf2f(((const u16*)Bsrc)[tid]); rv = bf2f(((const u16*)Rsrc)[tid]); }
        else      { bv = ((const float*)Bsrc)[tid];     rv = ((const float*)Rsrc)[tid]; }
        br[g * HID + tid] = bv + rv;
        if (g == 0 && tid == 0) *(int*)(ws + OFF_FLAG) = flag;
    }
}

// ------------- Kernel 1: xw[m][n] = sum_k X[m][k]*W_g[n&255][k] + b[n]+rot[n], bf16 out ---------
__global__ __launch_bounds__(256) void xw_gemm(const void* X, char* ws, int mbase)
{
    __shared__ u16 As[128][72];
    __shared__ u16 Bs[128][72];
    const int flag = *(const int*)(ws + OFF_FLAG);
    const u16*   Wc = (const u16*)(ws + OFF_WC);
    const float* br = (const float*)(ws + OFF_BR);
    u16* xw = (u16*)(ws + OFF_XW);

    const int tid  = threadIdx.x;
    const int lane = tid & 63;
    const int w    = tid >> 6;
    const int l15  = lane & 15;
    const int quad = lane >> 4;
    const int m0   = blockIdx.x * 128;
    const int n0   = blockIdx.y * 128;
    const int g    = n0 >> 8;
    const int rb   = n0 & 255;

    const u16* X16 = (const u16*)X;
    const float* X32 = (const float*)X;

    size_t aoff[4]; const u16* pB[4]; u16 *sA[4], *sB[4];
#pragma unroll
    for (int c = 0; c < 4; ++c) {
        int idx = c * 256 + tid;
        int row = idx >> 3;
        int cc  = idx & 7;
        aoff[c] = (size_t)(mbase + m0 + row) * IND + cc * 8;
        pB[c]   = Wc + (size_t)g * WGELEM + (size_t)(rb + row) * WROW + cc * 8;
        sA[c]   = &As[row][cc * 8];
        sB[c]   = &Bs[row][cc * 8];
    }

    f32x4 acc[4][4] = {};
    const int wr = (w >> 1) * 64;
    const int wc = (w & 1) * 64;

    for (int k0 = 0; k0 < IND; k0 += 64) {
        if (flag) {
#pragma unroll
            for (int c = 0; c < 4; ++c)
                *(uint4*)sA[c] = *(const uint4*)(X16 + aoff[c] + k0);
        } else {
#pragma unroll
            for (int c = 0; c < 4; ++c) {
                const float* p = X32 + aoff[c] + k0;
                float4 a = *(const float4*)p;
                float4 b = *(const float4*)(p + 4);
                u32 w0 = (u32)f2bf(a.x) | ((u32)f2bf(a.y) << 16);
                u32 w1 = (u32)f2bf(a.z) | ((u32)f2bf(a.w) << 16);
                u32 w2 = (u32)f2bf(b.x) | ((u32)f2bf(b.y) << 16);
                u32 w3 = (u32)f2bf(b.z) | ((u32)f2bf(b.w) << 16);
                *(uint4*)sA[c] = make_uint4(w0, w1, w2, w3);
            }
        }
#pragma unroll
        for (int c = 0; c < 4; ++c)
            *(uint4*)sB[c] = *(const uint4*)(pB[c] + k0);
        __syncthreads();
#pragma unroll
        for (int ks = 0; ks < 2; ++ks) {
            const int kk = ks * 32 + quad * 8;
            bf16x8 af[4], bfr[4];
#pragma unroll
            for (int i = 0; i < 4; ++i) af[i]  = *(const bf16x8*)&As[wr + i*16 + l15][kk];
#pragma unroll
            for (int j = 0; j < 4; ++j) bfr[j] = *(const bf16x8*)&Bs[wc + j*16 + l15][kk];
#pragma unroll
            for (int i = 0; i < 4; ++i)
#pragma unroll
                for (int j = 0; j < 4; ++j)
                    acc[i][j] = __builtin_amdgcn_mfma_f32_16x16x32_bf16(af[i], bfr[j], acc[i][j], 0, 0, 0);
        }
        __syncthreads();
    }

    float biasv[4];
#pragma unroll
    for (int j = 0; j < 4; ++j)
        biasv[j] = br[g * HID + rb + wc + j*16 + l15];
#pragma unroll
    for (int i = 0; i < 4; ++i)
#pragma unroll
        for (int j = 0; j < 4; ++j)
#pragma unroll
            for (int r = 0; r < 4; ++r) {
                int mrow = m0 + wr + i*16 + quad*4 + r;
                int ncol = n0 + wc + j*16 + l15;
                xw[(size_t)mrow * 1024 + ncol] = f2bf(acc[i][j][r] + biasv[j]);
            }
}

// ------------- Kernel 2: recurrence, Wh register-resident. -------------------------------------
// 64 blocks = 16 batch-groups x 4 hid-slices. Block = 4 waves (1/SIMD, <=512 VGPR).
// Wave w = gate w, owns Wh[gate w][slice cols 64][k 256] in 128 VGPRs. Zero Wh traffic in loop.
//
// Exchange protocol: NO acquire/release fences. On gfx950 an agent-scope acq/rel fence lowers
// to buffer_inv/buffer_wbl2 L2 cache walks -- executed per step per block (and per spin poll!)
// they are pure cache-maintenance latency. Instead the exchanged h values and counters are
// themselves RELAXED AGENT atomics, which lower to single global_load/store with sc0 sc1
// (performed at the Infinity-Cache coherence point, bypassing the non-coherent per-XCD L2).
// Ordering is structural: h loads complete before use (vmcnt), use precedes the pre-signal
// __syncthreads (which drains vmcnt(0)), which precedes the relaxed fetch_add. A[t]==4
// therefore still proves peers both published h_t AND finished reading h_{t-1} => double
// buffer stays race-free.
//
// Block remap: g = blockIdx&15, s = blockIdx>>4, so a group's 4 blocks {g,g+16,g+32,g+48}
// land on the same XCD under round-robin dispatch (all == g mod 8) for L2/xw locality.
__global__ __launch_bounds__(256, 1) void lstm_rec(char* ws, void* outv, int t0, int nsteps)
{
    __shared__ float pre[4][16][68];   // [gate][batch row][hid col] padded: quads land 2-way
    const int flag = *(const int*)(ws + OFF_FLAG);
    const u16*  Wc = (const u16*)(ws + OFF_WC);
    const u16*  xw = (const u16*)(ws + OFF_XW);
    u16*   hbuf = (u16*)(ws + OFF_HB);          // [2][256][256] bf16
    float* cst  = (float*)(ws + OFF_CST);
    int*   cnt  = (int*)(ws + OFF_CNT);         // [t][16 groups]
    u16*   out16 = (u16*)outv;
    float* out32 = (float*)outv;

    const int tid  = threadIdx.x;
    const int lane = tid & 63;
    const int w    = tid >> 6;        // wave index = gate
    const int l15  = lane & 15;
    const int quad = lane >> 4;
    const int g    = blockIdx.x & 15; // batch group: rows g*16..+15 (same-XCD peers)
    const int s    = blockIdx.x >> 4; // hid slice: cols s*64..+63
    const int b0   = g * 16;
    const int s0   = s * 64;

    // ---- load Wh slice into registers: wh[j][ks] = W[gate w][n=s0+j*16+l15][k=ks*32+quad*8 ..+7]
    bf16x8 wh[4][8];
    {
        const u16* base = Wc + (size_t)w * WGELEM + 512 + quad * 8;
#pragma unroll
        for (int j = 0; j < 4; ++j)
#pragma unroll
            for (int ks = 0; ks < 8; ++ks)
                wh[j][ks] = *(const bf16x8*)(base + (size_t)(s0 + j*16 + l15) * WROW + ks*32);
    }

    // pointwise ownership: thread owns batch row prow, cols s0+pc0..+3
    const int prow = tid >> 4;
    const int pc0  = (tid & 15) * 4;
    float c0v, c1v, c2v, c3v;
    if (t0 == 0) {
        c0v = c1v = c2v = c3v = 0.f;
        __hip_atomic_store((u64*)&hbuf[(size_t)(b0 + prow) * HID + s0 + pc0], 0ULL,
                           __ATOMIC_RELAXED, __HIP_MEMORY_SCOPE_AGENT);   // h_0 slice (parity 0)
        __syncthreads();                                                   // drains the stores
        if (tid == 0)
            __hip_atomic_fetch_add(&cnt[0*16 + g], 1, __ATOMIC_RELAXED, __HIP_MEMORY_SCOPE_AGENT);
    } else {
        float4 c4 = *(const float4*)&cst[(size_t)(b0 + prow) * HID + s0 + pc0];
        c0v = c4.x; c1v = c4.y; c2v = c4.z; c3v = c4.w;
    }

    float hlast[4] = {0.f, 0.f, 0.f, 0.f};

    for (int t = t0; t < t0 + nsteps; ++t) {
        const int p = t & 1;

        // x-side preacts for this step: independent of h. Issue BEFORE the wait so their
        // HBM latency (and last step's output-store acks) drain during the spin.
        u32 xp[4][2];
        {
            const u16* xrow = xw + (size_t)(t - t0) * 262144 + (size_t)(b0 + prow) * 1024 + s0 + pc0;
#pragma unroll
            for (int gg = 0; gg < 4; ++gg) {
                uint2 v = *(const uint2*)(xrow + gg * 256);
                xp[gg][0] = v.x; xp[gg][1] = v.y;
            }
        }

        if (tid == 0) {
            while (__hip_atomic_load(&cnt[t*16 + g], __ATOMIC_RELAXED, __HIP_MEMORY_SCOPE_AGENT) < 4) {
                __builtin_amdgcn_s_sleep(2);   // be polite to the LLC while polling
            }
        }
        __syncthreads();   // broadcast spin result; no fence needed (h loads below bypass L1/L2)

        // A frags: h_t[m=l15][k=quad*8+ks*32 ..+7] for batch rows b0..b0+15 (sc0/sc1 loads)
        bf16x8 af[8];
        {
            const u64* hrow = (const u64*)(hbuf + (size_t)p * 65536 + (size_t)(b0 + l15) * HID + quad * 8);
#pragma unroll
            for (int ks = 0; ks < 8; ++ks) {
                union { bf16x8 v; u64 q[2]; } uu;
                uu.q[0] = __hip_atomic_load(hrow + ks*8 + 0, __ATOMIC_RELAXED, __HIP_MEMORY_SCOPE_AGENT);
                uu.q[1] = __hip_atomic_load(hrow + ks*8 + 1, __ATOMIC_RELAXED, __HIP_MEMORY_SCOPE_AGENT);
                af[ks] = uu.v;
            }
        }

        f32x4 acc[4] = {};
#pragma unroll
        for (int ks = 0; ks < 8; ++ks)
#pragma unroll
            for (int j = 0; j < 4; ++j)
                acc[j] = __builtin_amdgcn_mfma_f32_16x16x32_bf16(af[ks], wh[j][ks], acc[j], 0, 0, 0);

        // preacts -> LDS for gate combine. C/D: row=quad*4+r, col(within n-tile)=l15
#pragma unroll
        for (int j = 0; j < 4; ++j)
#pragma unroll
            for (int r = 0; r < 4; ++r)
                pre[w][quad*4 + r][j*16 + l15] = acc[j][r];
        __syncthreads();

        // pointwise: 4 elems per thread
        float4 pf = *(const float4*)&pre[0][prow][pc0];
        float4 pi = *(const float4*)&pre[1][prow][pc0];
        float4 pu = *(const float4*)&pre[2][prow][pc0];
        float4 po = *(const float4*)&pre[3][prow][pc0];
        float xf[4][4];
#pragma unroll
        for (int gg = 0; gg < 4; ++gg) {
            xf[gg][0] = bf2f((u16)(xp[gg][0] & 0xffff));
            xf[gg][1] = bf2f((u16)(xp[gg][0] >> 16));
            xf[gg][2] = bf2f((u16)(xp[gg][1] & 0xffff));
            xf[gg][3] = bf2f((u16)(xp[gg][1] >> 16));
        }
        float hf[4];
        {
            float fv, iv, uv, ov;
            fv = sigm(pf.x + xf[0][0]); iv = sigm(pi.x + xf[1][0]);
            uv = sigm(pu.x + xf[2][0]); ov = sigm(po.x + xf[3][0]);
            c0v = fv * c0v + iv * uv; hf[0] = ov * tanh_fast(c0v);
            fv = sigm(pf.y + xf[0][1]); iv = sigm(pi.y + xf[1][1]);
            uv = sigm(pu.y + xf[2][1]); ov = sigm(po.y + xf[3][1]);
            c1v = fv * c1v + iv * uv; hf[1] = ov * tanh_fast(c1v);
            fv = sigm(pf.z + xf[0][2]); iv = sigm(pi.z + xf[1][2]);
            uv = sigm(pu.z + xf[2][2]); ov = sigm(po.z + xf[3][2]);
            c2v = fv * c2v + iv * uv; hf[2] = ov * tanh_fast(c2v);
            fv = sigm(pf.w + xf[0][3]); iv = sigm(pi.w + xf[1][3]);
            uv = sigm(pu.w + xf[2][3]); ov = sigm(po.w + xf[3][3]);
            c3v = fv * c3v + iv * uv; hf[3] = ov * tanh_fast(c3v);
        }
        u16 hb0 = f2bf(hf[0]), hb1 = f2bf(hf[1]), hb2 = f2bf(hf[2]), hb3 = f2bf(hf[3]);
        u64 hpack = (u64)hb0 | ((u64)hb1 << 16) | ((u64)hb2 << 32) | ((u64)hb3 << 48);

        // h_{t+1} slice -> exchange buffer (parity 1-p), sc0/sc1 write-through to coherence point
        __hip_atomic_store((u64*)&hbuf[(size_t)(1 - p) * 65536 + (size_t)(b0 + prow) * HID + s0 + pc0],
                           hpack, __ATOMIC_RELAXED, __HIP_MEMORY_SCOPE_AGENT);

        asm volatile("s_waitcnt vmcnt(0)" ::: "memory");  // belt+braces: h stores acked pre-barrier
        __syncthreads();      // all threads' exchange stores drained before the signal
        if (tid == 0)
            __hip_atomic_fetch_add(&cnt[(t+1)*16 + g], 1, __ATOMIC_RELAXED, __HIP_MEMORY_SCOPE_AGENT);

        // outputs[t]: AFTER the signal -- store-acks drain during next step's spin, off the path
        if (flag) {
            *(u64*)&out16[(size_t)t * 65536 + (size_t)(b0 + prow) * HID + s0 + pc0] = hpack;
        } else {
            *(float4*)&out32[(size_t)t * 65536 + (size_t)(b0 + prow) * HID + s0 + pc0] =
                make_float4(hf[0], hf[1], hf[2], hf[3]);
        }
        hlast[0] = hf[0]; hlast[1] = hf[1]; hlast[2] = hf[2]; hlast[3] = hf[3];
    }

    // persist c for next chunk
    *(float4*)&cst[(size_t)(b0 + prow) * HID + s0 + pc0] = make_float4(c0v, c1v, c2v, c3v);

    if (t0 + nsteps == SEQ) {   // final hx, cx
        size_t base = (size_t)SEQ * 65536;
        size_t idx = (size_t)(b0 + prow) * HID + s0 + pc0;
        if (flag) {
            *(u64*)&out16[base + idx] = (u64)f2bf(hlast[0]) | ((u64)f2bf(hlast[1]) << 16)
                                      | ((u64)f2bf(hlast[2]) << 32) | ((u64)f2bf(hlast[3]) << 48);
            *(u64*)&out16[base + 65536 + idx] = (u64)f2bf(c0v) | ((u64)f2bf(c1v) << 16)
                                              | ((u64)f2bf(c2v) << 32) | ((u64)f2bf(c3v) << 48);
        } else {
            *(float4*)&out32[base + idx] = make_float4(hlast[0], hlast[1], hlast[2], hlast[3]);
            *(float4*)&out32[base + 65536 + idx] = make_float4(c0v, c1v, c2v, c3v);
        }
    }
}

extern "C" void kernel_launch(void* const* d_in, const int* in_sizes, int n_in,
                              void* d_out, int out_size, void* d_ws, size_t ws_size,
                              hipStream_t stream) {
    // dict order: inputs, Wf,bf,rf, Wi,bi,ri, Wu,bu,ru, Wo,bo,ro
    const void* X = d_in[0];
    char* ws = (char*)d_ws;

    long long avail = (long long)ws_size - (long long)OFF_XW;
    int CH = (int)(avail / XW_STEP_BYTES);
    if (CH < 1)   CH = 1;
    if (CH > SEQ) CH = SEQ;

    hipLaunchKernelGGL(convert_w, dim3(96, 4), dim3(256), 0, stream,
        d_in[1], d_in[4], d_in[7], d_in[10],
        d_in[2], d_in[5], d_in[8], d_in[11],
        d_in[3], d_in[6], d_in[9], d_in[12], ws);

    for (int t0 = 0; t0 < SEQ; t0 += CH) {
        int ns = (SEQ - t0 < CH) ? (SEQ - t0) : CH;
        hipLaunchKernelGGL(xw_gemm, dim3(ns * 2, 8), dim3(256), 0, stream, X, ws, t0 * 256);
        hipLaunchKernelGGL(lstm_rec, dim3(64), dim3(256), 0, stream, ws, d_out, t0, ns);
    }
}